// Round 13
// baseline (1150.035 us; speedup 1.0000x reference)
//
#include <hip/hip_runtime.h>
#include <hip/hip_cooperative_groups.h>

namespace cg = cooperative_groups;

// GraphSAGE (2 SAGEConv mean-agg layers + linear head) on MI355X.
// N=100000 nodes, E=1600000 edges, D=64 channels, OUT=32.
//
// Round-13: cooperative mega-kernel — all 5 stages (rcur init, bin+prep,
// build_csr, fused layer1, fused layer2+head) in ONE dispatch with
// grid.sync() between stages. Kills ~17us of dispatch gaps. Stage bodies
// are the verified r12 code as __device__ functions (BCHUNK 4096->2048 to
// fit 8 blocks/CU LDS). Fallback to the 5-dispatch path if cooperative
// launch is unsupported.

#define D 64
#define OUTD 32
#define REG_SHIFT 8
#define REG_SIZE 256
#define BCHUNK 2048
#define PADQ 16                  // pad node lists to multiple of 16
#define CAP 5120                 // ebuf capacity per region
#define OUTCAP 8960              // colP capacity per region
#define MEGA_GRID 2048           // 8 blocks/CU x 256 CU

// ---------------- workspace layout (int units) ----------------
#define OFF_RCUR     64         // 512
#define OFF_DEG      576        // N padded-deg
#define OFF_ROWSTART 100928     // N
#define OFF_INV      201280     // N floats
#define OFF_COL      301632     // 391*OUTCAP
#define OFF_EBUF     3804992    // 391*CAP
#define OFF_XB       5806912    // (N+1)*32
#define OFF_H1B      9006944    // (N+1)*32
#define OFF_WC1      15406976   // 4096
#define OFF_WC2      15411072   // 4096
#define OFF_WHB      15415168   // 1024

typedef __attribute__((ext_vector_type(8))) short bf16x8;
typedef __attribute__((ext_vector_type(4))) float f32x4;
typedef __attribute__((ext_vector_type(2))) float f32x2;

struct SmemBin {
    int stage[BCHUNK];                // 8 KB
    unsigned short rgn[BCHUNK];       // 4 KB (first 512 ints double as scan scratch)
    int hist[512];                    // 2 KB
    int lbase[512];                   // 2 KB
    int startr[512];                  // 2 KB
};
struct SmemBuild { int hist[REG_SIZE], cur[REG_SIZE], sA[REG_SIZE], sB[REG_SIZE]; };
struct SmemFused { unsigned meanT[16 * 32]; unsigned short hT[16 * 64]; };
union SmemAll { SmemBin bin; SmemBuild bld; SmemFused fus; };

__device__ __forceinline__ unsigned short bf16rne(float x) {
    unsigned u = __float_as_uint(x);
    unsigned r = (u + 0x7FFFu + ((u >> 16) & 1u)) >> 16;
    return (unsigned short)r;
}

// Per-block edge-layout detection (int64 iff all 64 high dwords zero).
__device__ __forceinline__ int detect_mode_local(const int* __restrict__ e32) {
    int vflag = 0;
    if (threadIdx.x < 64) vflag = (e32[2 * threadIdx.x + 1] != 0);
    return __syncthreads_or(vflag) ? 0 : 1;
}

// ---------------- stage bodies (verified r12 logic) ----------------

__device__ __forceinline__ void bin_body(
        int vb, int mode, const int* __restrict__ e32, int* __restrict__ rcur,
        int* __restrict__ ebuf, int E, int NR, SmemBin& sm) {
    int t = threadIdx.x;
    int* s1 = (int*)sm.rgn;           // scan scratch; rgn written only later
    int base = vb * BCHUNK;
    for (int i = t; i < 512; i += 256) sm.hist[i] = 0;
    __syncthreads();
    for (int j = t; j < BCHUNK; j += 256) {
        int i = base + j;
        if (i < E) {
            int d = mode ? e32[2 * (E + i)] : e32[E + i];
            atomicAdd(&sm.hist[d >> REG_SHIFT], 1);
        }
    }
    __syncthreads();
    {
        int* a = sm.lbase; int* b = s1;
        for (int i = t; i < 512; i += 256) a[i] = sm.hist[i];
        __syncthreads();
        for (int off = 1; off < 512; off <<= 1) {
            for (int i = t; i < 512; i += 256)
                b[i] = a[i] + ((i >= off) ? a[i - off] : 0);
            __syncthreads();
            int* tmp = a; a = b; b = tmp;
        }
        for (int i = t; i < 512; i += 256) {
            int incl = a[i];
            int ex = incl - sm.hist[i];
            __syncthreads();
            sm.lbase[i] = ex;
        }
        __syncthreads();
    }
    for (int i = t; i < 512; i += 256) {
        int st = 0;
        if (i < NR && sm.hist[i] > 0) {
            st = atomicAdd(&rcur[i], sm.hist[i]);
            int lim = (i + 1) * CAP - sm.hist[i];
            if (st > lim) st = lim;            // safety clamp
        }
        sm.startr[i] = st;
    }
    __syncthreads();
    for (int i = t; i < 512; i += 256) sm.hist[i] = 0;
    __syncthreads();
    for (int j = t; j < BCHUNK; j += 256) {
        int i = base + j;
        if (i < E) {
            int s = mode ? e32[2 * i]       : e32[i];
            int d = mode ? e32[2 * (E + i)] : e32[E + i];
            int r = d >> REG_SHIFT;
            int o = atomicAdd(&sm.hist[r], 1);
            int pos = sm.lbase[r] + o;
            sm.stage[pos] = ((d & (REG_SIZE - 1)) << 24) | s;
            sm.rgn[pos] = (unsigned short)r;
        }
    }
    __syncthreads();
    int count = E - base; if (count > BCHUNK) count = BCHUNK;
    for (int i = t; i < count; i += 256) {
        int r = sm.rgn[i];
        ebuf[sm.startr[r] + (i - sm.lbase[r])] = sm.stage[i];
    }
    __syncthreads();                  // smem safe for next virtual block
}

__device__ __forceinline__ void prep_body(
        int vb, const float* __restrict__ x, unsigned short* __restrict__ xb,
        unsigned short* __restrict__ h1b,
        const float* __restrict__ w1l, const float* __restrict__ w1r,
        const float* __restrict__ w2l, const float* __restrict__ w2r,
        const float* __restrict__ wh,
        unsigned short* __restrict__ wcat1, unsigned short* __restrict__ wcat2,
        unsigned short* __restrict__ whb, int n4, int N) {
    int i = vb * 256 + (int)threadIdx.x;
    if (i < n4) {
        float4 v = ((const float4*)x)[i];
        unsigned lo = (unsigned)bf16rne(v.x) | ((unsigned)bf16rne(v.y) << 16);
        unsigned hi = (unsigned)bf16rne(v.z) | ((unsigned)bf16rne(v.w) << 16);
        ((uint2*)xb)[i] = make_uint2(lo, hi);
        return;
    }
    int j = i - n4;
    if (j < 16) {
        ((uint2*)xb)[(size_t)N * 16 + j] = make_uint2(0u, 0u);
    } else if (j < 32) {
        ((uint2*)h1b)[(size_t)N * 16 + (j - 16)] = make_uint2(0u, 0u);
    } else if (j < 32 + 8192) {
        int q = j - 32;
        int o = q >> 7, k = q & 127;
        wcat1[q] = bf16rne(k < 64 ? w1l[o * 64 + k] : w1r[o * 64 + k - 64]);
    } else if (j < 32 + 16384) {
        int q = j - 32 - 8192;
        int o = q >> 7, k = q & 127;
        wcat2[q] = bf16rne(k < 64 ? w2l[o * 64 + k] : w2r[o * 64 + k - 64]);
    } else if (j < 32 + 16384 + 2048) {
        int q = j - 32 - 16384;
        whb[q] = bf16rne(wh[q]);
    }
}

__device__ __forceinline__ void build_body(
        int r, const int* __restrict__ ebuf, const int* __restrict__ rcur,
        int* __restrict__ degP, int* __restrict__ rowStartP, float* __restrict__ inv,
        int* __restrict__ colP, int N, SmemBuild& sm) {
    int t = threadIdx.x;
    int lo = r << REG_SHIFT;
    int e0 = r * CAP, e1 = rcur[r];
    int colPbase = r * OUTCAP;
    sm.hist[t] = 0;
    __syncthreads();
    for (int i = e0 + t; i < e1; i += 256)
        atomicAdd(&sm.hist[((unsigned)ebuf[i]) >> 24], 1);
    __syncthreads();
    int v = sm.hist[t];
    int vp = (v + PADQ - 1) & ~(PADQ - 1);
    int* a = sm.sA; int* b = sm.sB;
    a[t] = vp;
    __syncthreads();
    for (int off = 1; off < 256; off <<= 1) {
        b[t] = a[t] + ((t >= off) ? a[t - off] : 0);
        __syncthreads();
        int* tmp = a; a = b; b = tmp;
    }
    int startP = colPbase + (a[t] - vp);
    int node = lo + t;
    if (node < N) {
        degP[node] = vp;
        rowStartP[node] = startP;
        inv[node] = 1.0f / (float)(v > 0 ? v : 1);
    }
    sm.cur[t] = startP;
    __syncthreads();
    for (int i = e0 + t; i < e1; i += 256) {
        int p = ebuf[i];
        int pos = atomicAdd(&sm.cur[((unsigned)p) >> 24], 1);
        colP[pos] = (p & 0xFFFFFF) << 7;        // byte offset
    }
    __syncthreads();
    int zoff = N << 7;
    for (int k = startP + v; k < startP + vp; ++k) colP[k] = zoff;
    __syncthreads();
}

// Fused SAGE layer body (verified r12): gather phase + MFMA dense (+ head).
template <bool HEAD>
__device__ __forceinline__ void fused_body(
        int tile,
        const unsigned short* __restrict__ hb,
        const int* __restrict__ rowStartP, const int* __restrict__ degPv,
        const int* __restrict__ colP, const float* __restrict__ invdeg,
        const unsigned short* __restrict__ wcat, const float* __restrict__ bias,
        unsigned short* __restrict__ houtb,
        const unsigned short* __restrict__ whb, const float* __restrict__ bh,
        float* __restrict__ outp, SmemFused& sm, int n) {
    const int lane = threadIdx.x & 63;
    const int w    = threadIdx.x >> 6;
    const int half = lane >> 5, l31 = lane & 31;
    const int l15  = lane & 15, kg  = lane >> 4;
    const char* hbC = (const char*)hb;
    unsigned voff = (unsigned)(l31 << 2);

    const int nb = tile * 16;

    // phase 1: gather 4 nodes per wave
    for (int q = 0; q < 4; ++q) {
        int node = nb + w * 4 + q;
        int nodeC = node < n ? node : n - 1;
        nodeC = __builtin_amdgcn_readfirstlane(nodeC);
        int rs = rowStartP[nodeC];
        int dgp = degPv[nodeC];

        f32x2 a0 = {0.f, 0.f}, a1 = {0.f, 0.f}, a2 = {0.f, 0.f}, a3 = {0.f, 0.f};
        f32x2 a4 = {0.f, 0.f}, a5 = {0.f, 0.f}, a6 = {0.f, 0.f}, a7 = {0.f, 0.f};

        for (int base = 0; base < dgp; base += 64) {
            int cv = colP[rs + base + lane];
            int m = dgp - base; if (m > 64) m = 64;
            int pairs = m >> 1;             // multiple of 8
            int pb = half;                  // shfl index: 2*p + half
            for (int p = 0; p < pairs; p += 8) {
#define G(j, A) { \
                int cb = __shfl(cv, pb + 2 * (j)); \
                unsigned u = *(const unsigned*)(hbC + ((unsigned)cb + voff)); \
                f32x2 ww = {__uint_as_float(u << 16), __uint_as_float(u & 0xFFFF0000u)}; \
                A += ww; }
                G(0, a0)  G(1, a1)  G(2, a2)  G(3, a3)
                G(4, a4)  G(5, a5)  G(6, a6)  G(7, a7)
#undef G
                pb += 16;
            }
        }
        f32x2 s = ((a0 + a1) + (a2 + a3)) + ((a4 + a5) + (a6 + a7));
        float s0 = s.x + __shfl_xor(s.x, 32);
        float s1 = s.y + __shfl_xor(s.y, 32);
        float iv = invdeg[nodeC];
        if (!half) {
            int local = w * 4 + q;
            unsigned mo = (unsigned)bf16rne(s0 * iv) | ((unsigned)bf16rne(s1 * iv) << 16);
            int cb = l31 >> 2;
            sm.meanT[local * 32 + ((cb ^ (local & 7)) << 2) + (l31 & 3)] = mo;
        }
    }
    __syncthreads();

    // phase 2: dense, wave w -> output quadrant nt=w
    const int nt = w;
    bf16x8 Am[2];
#pragma unroll
    for (int s = 0; s < 2; ++s) {
        int cb = s * 4 + kg;
        Am[s] = *(const bf16x8*)&sm.meanT[l15 * 32 + ((cb ^ (l15 & 7)) << 2)];
    }
    int arow = nb + l15; if (arow >= n) arow = n - 1;
    const unsigned short* orow = hb + (size_t)arow * 64 + kg * 8;
    bf16x8 Ao0 = *(const bf16x8*)(orow);
    bf16x8 Ao1 = *(const bf16x8*)(orow + 32);
    const unsigned short* wrow = wcat + (nt * 16 + l15) * 128 + kg * 8;
    bf16x8 B0 = *(const bf16x8*)(wrow);
    bf16x8 B1 = *(const bf16x8*)(wrow + 32);
    bf16x8 B2 = *(const bf16x8*)(wrow + 64);
    bf16x8 B3 = *(const bf16x8*)(wrow + 96);

    float bc = bias[nt * 16 + l15];
    f32x4 a = {bc, bc, bc, bc};
    a = __builtin_amdgcn_mfma_f32_16x16x32_bf16(Am[0], B0, a, 0, 0, 0);
    a = __builtin_amdgcn_mfma_f32_16x16x32_bf16(Am[1], B1, a, 0, 0, 0);
    a = __builtin_amdgcn_mfma_f32_16x16x32_bf16(Ao0,  B2, a, 0, 0, 0);
    a = __builtin_amdgcn_mfma_f32_16x16x32_bf16(Ao1,  B3, a, 0, 0, 0);

    if constexpr (!HEAD) {
#pragma unroll
        for (int r = 0; r < 4; ++r) {
            int rw = nb + kg * 4 + r;
            float h = fmaxf(a[r], 0.0f);
            if (rw < n) houtb[(size_t)rw * 64 + nt * 16 + l15] = bf16rne(h);
        }
    } else {
        int bGlob = nt * 2 + (l15 >> 3);
        int n7 = l15 & 7;
#pragma unroll
        for (int r = 0; r < 4; ++r) {
            int m = kg * 4 + r;
            float h = fmaxf(a[r], 0.0f);
            sm.hT[m * 64 + ((bGlob ^ (m & 7)) * 8) + n7] = bf16rne(h);
        }
        __syncthreads();
        if (w < 2) {
            bf16x8 hA[2];
#pragma unroll
            for (int s = 0; s < 2; ++s) {
                int kb = s * 4 + kg;
                hA[s] = *(const bf16x8*)(sm.hT + l15 * 64 + ((kb ^ (l15 & 7)) * 8));
            }
            const unsigned short* hrow = whb + (w * 16 + l15) * 64 + kg * 8;
            bf16x8 H0 = *(const bf16x8*)(hrow);
            bf16x8 H1 = *(const bf16x8*)(hrow + 32);
            float bc2 = bh[w * 16 + l15];
            f32x4 a2 = {bc2, bc2, bc2, bc2};
            a2 = __builtin_amdgcn_mfma_f32_16x16x32_bf16(hA[0], H0, a2, 0, 0, 0);
            a2 = __builtin_amdgcn_mfma_f32_16x16x32_bf16(hA[1], H1, a2, 0, 0, 0);
#pragma unroll
            for (int r = 0; r < 4; ++r) {
                int rw = nb + kg * 4 + r;
                if (rw < n) outp[(size_t)rw * 32 + w * 16 + l15] = a2[r];
            }
        }
    }
}

// ---------------- cooperative mega-kernel ----------------
__global__ __launch_bounds__(256, 8) void mega(
        const int* __restrict__ e32, int E, int NR, int N, int n4,
        int* __restrict__ rcur, int* __restrict__ ebuf,
        int* __restrict__ degP, int* __restrict__ rowStartP,
        float* __restrict__ inv, int* __restrict__ colP,
        const float* __restrict__ x,
        unsigned short* __restrict__ xb, unsigned short* __restrict__ h1b,
        const float* __restrict__ w1l, const float* __restrict__ w1r,
        const float* __restrict__ w2l, const float* __restrict__ w2r,
        const float* __restrict__ wh,
        unsigned short* __restrict__ wcat1, unsigned short* __restrict__ wcat2,
        unsigned short* __restrict__ whb,
        const float* __restrict__ b1, const float* __restrict__ b2,
        const float* __restrict__ bh, float* __restrict__ outp) {
    __shared__ SmemAll sm;
    int mode = detect_mode_local(e32);
    int gt = blockIdx.x * 256 + (int)threadIdx.x;
    if (gt < NR) rcur[gt] = gt * CAP;
    cg::this_grid().sync();

    int bvirt = (E + BCHUNK - 1) / BCHUNK;
    int pvirt = (n4 + 32 + 16384 + 2048 + 255) / 256;
    for (int vb = blockIdx.x; vb < bvirt + pvirt; vb += gridDim.x) {
        if (vb < bvirt) bin_body(vb, mode, e32, rcur, ebuf, E, NR, sm.bin);
        else prep_body(vb - bvirt, x, xb, h1b, w1l, w1r, w2l, w2r, wh,
                       wcat1, wcat2, whb, n4, N);
    }
    cg::this_grid().sync();

    for (int r = blockIdx.x; r < NR; r += gridDim.x)
        build_body(r, ebuf, rcur, degP, rowStartP, inv, colP, N, sm.bld);
    cg::this_grid().sync();

    int ntiles = (N + 15) >> 4;
    for (int tb = blockIdx.x; tb < ntiles; tb += gridDim.x) {
        fused_body<false>(tb, xb, rowStartP, degP, colP, inv, wcat1, b1,
                          h1b, nullptr, nullptr, nullptr, sm.fus, N);
        __syncthreads();
    }
    cg::this_grid().sync();

    for (int tb = blockIdx.x; tb < ntiles; tb += gridDim.x) {
        fused_body<true>(tb, h1b, rowStartP, degP, colP, inv, wcat2, b2,
                         nullptr, whb, bh, outp, sm.fus, N);
        __syncthreads();
    }
}

// ---------------- fallback kernels (r12-equivalent, shared bodies) ----------------
__global__ void init_rcur_k(int* __restrict__ rcur, int NR) {
    int t = blockIdx.x * 256 + (int)threadIdx.x;
    if (t < NR) rcur[t] = t * CAP;
}

__global__ __launch_bounds__(256) void bin_prep_k(
        const int* __restrict__ e32, int* __restrict__ rcur, int* __restrict__ ebuf,
        int E, int NR, int bblocks,
        const float* __restrict__ x, unsigned short* __restrict__ xb,
        unsigned short* __restrict__ h1b,
        const float* __restrict__ w1l, const float* __restrict__ w1r,
        const float* __restrict__ w2l, const float* __restrict__ w2r,
        const float* __restrict__ wh,
        unsigned short* __restrict__ wcat1, unsigned short* __restrict__ wcat2,
        unsigned short* __restrict__ whb, int n4, int N) {
    __shared__ SmemBin sm;
    int mode = detect_mode_local(e32);
    if (blockIdx.x < (unsigned)bblocks)
        bin_body(blockIdx.x, mode, e32, rcur, ebuf, E, NR, sm);
    else
        prep_body(blockIdx.x - bblocks, x, xb, h1b, w1l, w1r, w2l, w2r, wh,
                  wcat1, wcat2, whb, n4, N);
}

__global__ __launch_bounds__(256) void build_k(
        const int* __restrict__ ebuf, const int* __restrict__ rcur,
        int* __restrict__ degP, int* __restrict__ rowStartP, float* __restrict__ inv,
        int* __restrict__ colP, int N) {
    __shared__ SmemBuild sm;
    build_body(blockIdx.x, ebuf, rcur, degP, rowStartP, inv, colP, N, sm);
}

template <bool HEAD>
__global__ __launch_bounds__(256, 8) void fused_k(
        const unsigned short* __restrict__ hb,
        const int* __restrict__ rowStartP, const int* __restrict__ degPv,
        const int* __restrict__ colP, const float* __restrict__ invdeg,
        const unsigned short* __restrict__ wcat, const float* __restrict__ bias,
        unsigned short* __restrict__ houtb,
        const unsigned short* __restrict__ whb, const float* __restrict__ bh,
        float* __restrict__ outp, int n) {
    __shared__ SmemFused sm;
    fused_body<HEAD>(blockIdx.x, hb, rowStartP, degPv, colP, invdeg, wcat, bias,
                     houtb, whb, bh, outp, sm, n);
}

extern "C" void kernel_launch(void* const* d_in, const int* in_sizes, int n_in,
                              void* d_out, int out_size, void* d_ws, size_t ws_size,
                              hipStream_t stream) {
    const int* e32   = (const int*)d_in[1];
    const float* x   = (const float*)d_in[0];
    const float* w1l = (const float*)d_in[2];
    const float* b1  = (const float*)d_in[3];
    const float* w1r = (const float*)d_in[4];
    const float* w2l = (const float*)d_in[5];
    const float* b2  = (const float*)d_in[6];
    const float* w2r = (const float*)d_in[7];
    const float* wh  = (const float*)d_in[8];
    const float* bh  = (const float*)d_in[9];
    float* out = (float*)d_out;

    int N = in_sizes[0] / D;   // 100000
    int E = in_sizes[1] / 2;   // 1600000
    int NR = (N + REG_SIZE - 1) >> REG_SHIFT;   // 391
    int n4 = N * D / 4;

    int* ws = (int*)d_ws;
    int*            rcur     = ws + OFF_RCUR;
    int*            degP     = ws + OFF_DEG;
    int*            rowStartP= ws + OFF_ROWSTART;
    float*          inv      = (float*)(ws + OFF_INV);
    int*            colP     = ws + OFF_COL;
    int*            ebuf     = ws + OFF_EBUF;
    unsigned short* xb       = (unsigned short*)(ws + OFF_XB);
    unsigned short* h1b      = (unsigned short*)(ws + OFF_H1B);
    unsigned short* wcat1    = (unsigned short*)(ws + OFF_WC1);
    unsigned short* wcat2    = (unsigned short*)(ws + OFF_WC2);
    unsigned short* whb      = (unsigned short*)(ws + OFF_WHB);

    int dev = 0;
    hipGetDevice(&dev);
    int coop = 0;
    hipDeviceGetAttribute(&coop, hipDeviceAttributeCooperativeLaunch, dev);

    if (coop) {
        void* args[] = {
            (void*)&e32, (void*)&E, (void*)&NR, (void*)&N, (void*)&n4,
            (void*)&rcur, (void*)&ebuf, (void*)&degP, (void*)&rowStartP,
            (void*)&inv, (void*)&colP, (void*)&x, (void*)&xb, (void*)&h1b,
            (void*)&w1l, (void*)&w1r, (void*)&w2l, (void*)&w2r, (void*)&wh,
            (void*)&wcat1, (void*)&wcat2, (void*)&whb,
            (void*)&b1, (void*)&b2, (void*)&bh, (void*)&out
        };
        hipError_t err = hipLaunchCooperativeKernel(
            mega, dim3(MEGA_GRID), dim3(256), args, 0u, stream);
        if (err == hipSuccess) return;
    }

    // ---------------- fallback: 5-dispatch path ----------------
    init_rcur_k<<<2, 256, 0, stream>>>(rcur, NR);
    int bblocks = (E + BCHUNK - 1) / BCHUNK;
    int pblocks = (n4 + 32 + 16384 + 2048 + 255) / 256;
    bin_prep_k<<<bblocks + pblocks, 256, 0, stream>>>(
        e32, rcur, ebuf, E, NR, bblocks,
        x, xb, h1b, w1l, w1r, w2l, w2r, wh, wcat1, wcat2, whb, n4, N);
    build_k<<<NR, 256, 0, stream>>>(ebuf, rcur, degP, rowStartP, inv, colP, N);

    int ntiles = (N + 15) / 16;
    fused_k<false><<<ntiles, 256, 0, stream>>>(
        xb, rowStartP, degP, colP, inv, wcat1, b1,
        h1b, nullptr, nullptr, nullptr, N);
    fused_k<true><<<ntiles, 256, 0, stream>>>(
        h1b, rowStartP, degP, colP, inv, wcat2, b2,
        nullptr, whb, bh, out, N);
}

// Round 14
// 137.437 us; speedup vs baseline: 8.3677x; 8.3677x over previous
//
#include <hip/hip_runtime.h>

// GraphSAGE (2 SAGEConv mean-agg layers + linear head) on MI355X.
// N=100000 nodes, E=1600000 edges, D=64 channels, OUT=32.
//
// Round-14: r13's cooperative mega-kernel catastrophically regressed (1150us,
// VALUBusy 4%) -> full revert to the verified r12 5-dispatch structure.
// One change vs r12: PADQ 16->8 (avg padded degree 22.6 -> 19.7, ~13% fewer
// gather loads); gather gains a 4-slot tail block (pairs % 4 == 0).

#define D 64
#define OUTD 32
#define REG_SHIFT 8
#define REG_SIZE 256
#define BCHUNK 4096
#define PADQ 8                   // pad node lists to multiple of 8
#define CAP 5120                 // ebuf capacity per region
#define OUTCAP 8960              // colP capacity per region (CAP + 256*7 = 6912 fits)

// ---------------- workspace layout (int units) ----------------
#define OFF_FLAG     0          // 64
#define OFF_RCUR     64         // 512
#define OFF_DEG      576        // N padded-deg (reserve 100352)
#define OFF_ROWSTART 100928     // N
#define OFF_INV      201280     // N floats
#define OFF_COL      301632     // 391*OUTCAP = 3503360
#define OFF_EBUF     3804992    // 391*CAP = 2001920
#define OFF_XB       5806912    // (N+1)*32
#define OFF_H1B      9006944    // (N+1)*32
#define OFF_WC1      15406976   // 4096
#define OFF_WC2      15411072   // 4096
#define OFF_WHB      15415168   // 1024

typedef __attribute__((ext_vector_type(8))) short bf16x8;
typedef __attribute__((ext_vector_type(4))) float f32x4;
typedef __attribute__((ext_vector_type(2))) float f32x2;

__device__ __forceinline__ unsigned short bf16rne(float x) {
    unsigned u = __float_as_uint(x);
    unsigned r = (u + 0x7FFFu + ((u >> 16) & 1u)) >> 16;
    return (unsigned short)r;
}

// Detect int64-vs-int32 edge layout + init per-region cursors to r*CAP.
__global__ void detect_init(const int* __restrict__ e32, int* __restrict__ flag,
                            int* __restrict__ rcur, int NR) {
    int t = threadIdx.x;                 // 512 threads
    if (t < 64) {
        int v = e32[2 * t + 1];
        unsigned long long m = __ballot(v != 0);
        if (t == 0) flag[0] = (m == 0ULL) ? 1 : 0;   // 1 => int64 layout
    }
    if (t < NR) rcur[t] = t * CAP;
}

// Fused: blocks < bblocks bin edges into region segments; the rest do prep
// (fp32->bf16 cast of x, zero rows, weight concat). Independent outputs.
__global__ __launch_bounds__(256) void bin_prep(
        const int* __restrict__ e32, const int* __restrict__ flag,
        int* __restrict__ rcur, int* __restrict__ ebuf, int E, int NR, int bblocks,
        const float* __restrict__ x, unsigned short* __restrict__ xb,
        unsigned short* __restrict__ h1b,
        const float* __restrict__ w1l, const float* __restrict__ w1r,
        const float* __restrict__ w2l, const float* __restrict__ w2r,
        const float* __restrict__ wh,
        unsigned short* __restrict__ wcat1, unsigned short* __restrict__ wcat2,
        unsigned short* __restrict__ whb, int n4, int N) {
    __shared__ int stage[BCHUNK];
    __shared__ unsigned short rgn[BCHUNK];
    __shared__ int hist[512], lbase[512], startr[512], s1[512];
    int t = threadIdx.x;

    if (blockIdx.x >= bblocks) {
        // ---------------- prep path ----------------
        int i = (blockIdx.x - bblocks) * 256 + t;
        if (i < n4) {
            float4 v = ((const float4*)x)[i];
            unsigned lo = (unsigned)bf16rne(v.x) | ((unsigned)bf16rne(v.y) << 16);
            unsigned hi = (unsigned)bf16rne(v.z) | ((unsigned)bf16rne(v.w) << 16);
            ((uint2*)xb)[i] = make_uint2(lo, hi);
            return;
        }
        int j = i - n4;
        if (j < 16) {
            ((uint2*)xb)[(size_t)N * 16 + j] = make_uint2(0u, 0u);
        } else if (j < 32) {
            ((uint2*)h1b)[(size_t)N * 16 + (j - 16)] = make_uint2(0u, 0u);
        } else if (j < 32 + 8192) {
            int q = j - 32;
            int o = q >> 7, k = q & 127;
            wcat1[q] = bf16rne(k < 64 ? w1l[o * 64 + k] : w1r[o * 64 + k - 64]);
        } else if (j < 32 + 16384) {
            int q = j - 32 - 8192;
            int o = q >> 7, k = q & 127;
            wcat2[q] = bf16rne(k < 64 ? w2l[o * 64 + k] : w2r[o * 64 + k - 64]);
        } else if (j < 32 + 16384 + 2048) {
            int q = j - 32 - 16384;
            whb[q] = bf16rne(wh[q]);
        }
        return;
    }

    // ---------------- bin path ----------------
    int mode = flag[0];
    int base = blockIdx.x * BCHUNK;
    for (int i = t; i < 512; i += 256) hist[i] = 0;
    __syncthreads();
    for (int j = t; j < BCHUNK; j += 256) {
        int i = base + j;
        if (i < E) {
            int d = mode ? e32[2 * (E + i)] : e32[E + i];
            atomicAdd(&hist[d >> REG_SHIFT], 1);
        }
    }
    __syncthreads();
    {
        int* a = lbase; int* b = s1;
        for (int i = t; i < 512; i += 256) a[i] = hist[i];
        __syncthreads();
        for (int off = 1; off < 512; off <<= 1) {
            for (int i = t; i < 512; i += 256)
                b[i] = a[i] + ((i >= off) ? a[i - off] : 0);
            __syncthreads();
            int* tmp = a; a = b; b = tmp;
        }
        for (int i = t; i < 512; i += 256) {
            int incl = a[i];
            int ex = incl - hist[i];
            __syncthreads();
            lbase[i] = ex;
        }
        __syncthreads();
    }
    for (int i = t; i < 512; i += 256) {
        int st = 0;
        if (i < NR && hist[i] > 0) {
            st = atomicAdd(&rcur[i], hist[i]);
            int lim = (i + 1) * CAP - hist[i];
            if (st > lim) st = lim;            // safety clamp (won't trigger)
        }
        startr[i] = st;
    }
    __syncthreads();
    for (int i = t; i < 512; i += 256) hist[i] = 0;
    __syncthreads();
    for (int j = t; j < BCHUNK; j += 256) {
        int i = base + j;
        if (i < E) {
            int s = mode ? e32[2 * i]       : e32[i];
            int d = mode ? e32[2 * (E + i)] : e32[E + i];
            int r = d >> REG_SHIFT;
            int o = atomicAdd(&hist[r], 1);
            int pos = lbase[r] + o;
            stage[pos] = ((d & (REG_SIZE - 1)) << 24) | s;
            rgn[pos] = (unsigned short)r;
        }
    }
    __syncthreads();
    int count = E - base; if (count > BCHUNK) count = BCHUNK;
    for (int i = t; i < count; i += 256) {
        int r = rgn[i];
        ebuf[startr[r] + (i - lbase[r])] = stage[i];
    }
}

// Per-region local CSR build with zero-row padding (byte offsets, x8 pad).
__global__ __launch_bounds__(256) void build_csr(
        const int* __restrict__ ebuf, const int* __restrict__ rcur,
        int* __restrict__ degP, int* __restrict__ rowStartP, float* __restrict__ inv,
        int* __restrict__ colP, int N) {
    __shared__ int hist[REG_SIZE], cur[REG_SIZE], sA[REG_SIZE], sB[REG_SIZE];
    int r = blockIdx.x;
    int t = threadIdx.x;
    int lo = r << REG_SHIFT;
    int e0 = r * CAP, e1 = rcur[r];
    int colPbase = r * OUTCAP;
    hist[t] = 0;
    __syncthreads();
    for (int i = e0 + t; i < e1; i += 256)
        atomicAdd(&hist[((unsigned)ebuf[i]) >> 24], 1);
    __syncthreads();
    int v = hist[t];
    int vp = (v + PADQ - 1) & ~(PADQ - 1);
    int* a = sA; int* b = sB;
    a[t] = vp;
    __syncthreads();
    for (int off = 1; off < 256; off <<= 1) {
        b[t] = a[t] + ((t >= off) ? a[t - off] : 0);
        __syncthreads();
        int* tmp = a; a = b; b = tmp;
    }
    int startP = colPbase + (a[t] - vp);
    int node = lo + t;
    if (node < N) {
        degP[node] = vp;
        rowStartP[node] = startP;
        inv[node] = 1.0f / (float)(v > 0 ? v : 1);
    }
    cur[t] = startP;
    __syncthreads();
    for (int i = e0 + t; i < e1; i += 256) {
        int p = ebuf[i];
        int pos = atomicAdd(&cur[((unsigned)p) >> 24], 1);
        colP[pos] = (p & 0xFFFFFF) << 7;        // byte offset
    }
    __syncthreads();
    int zoff = N << 7;
    for (int k = startP + v; k < startP + vp; ++k) colP[k] = zoff;
}

// Fused SAGE layer: gather (phase 1) + MFMA dense (phase 2) (+ head).
// One 16-node tile per block (4 waves). Phase 1: wave w gathers nodes
// w*4..w*4+3 (r11 loop + 4-slot tail), staging packed means into a
// swizzled LDS tile. Phase 2: wave w computes output quadrant nt=w via
// 4 mfma_16x16x32 (mean frags from LDS, own frags from global = gather src).
// HEAD: h2 tile staged to shared swizzled LDS; waves 0-1 do the head MFMAs.
template <bool HEAD>
__global__ __launch_bounds__(256, 8) void fused_layer(
        const unsigned short* __restrict__ hb,       // gather + own source
        const int* __restrict__ rowStartP, const int* __restrict__ degPv,
        const int* __restrict__ colP, const float* __restrict__ invdeg,
        const unsigned short* __restrict__ wcat,     // [64][128]
        const float* __restrict__ bias,              // [64]
        unsigned short* __restrict__ houtb,          // !HEAD out (bf16)
        const unsigned short* __restrict__ whb,      // [32][64]
        const float* __restrict__ bh,                // [32]
        float* __restrict__ outp,                    // [N][32]
        int n) {
    __shared__ unsigned meanT[16 * 32];              // swizzled (16B blocks)
    __shared__ unsigned short hT[HEAD ? 16 * 64 : 64];

    const int lane = threadIdx.x & 63;
    const int w    = threadIdx.x >> 6;
    const int half = lane >> 5, l31 = lane & 31;
    const int l15  = lane & 15, kg  = lane >> 4;
    const char* hbC = (const char*)hb;
    unsigned voff = (unsigned)(l31 << 2);

    const int nb = blockIdx.x * 16;

    // ---------------- phase 1: gather 4 nodes per wave ----------------
    for (int q = 0; q < 4; ++q) {
        int node = nb + w * 4 + q;
        int nodeC = node < n ? node : n - 1;
        nodeC = __builtin_amdgcn_readfirstlane(nodeC);
        int rs = rowStartP[nodeC];
        int dgp = degPv[nodeC];

        f32x2 a0 = {0.f, 0.f}, a1 = {0.f, 0.f}, a2 = {0.f, 0.f}, a3 = {0.f, 0.f};
        f32x2 a4 = {0.f, 0.f}, a5 = {0.f, 0.f}, a6 = {0.f, 0.f}, a7 = {0.f, 0.f};

        for (int base = 0; base < dgp; base += 64) {
            int cv = colP[rs + base + lane];
            int m = dgp - base; if (m > 64) m = 64;
            int pairs = m >> 1;             // multiple of 4
            int pb = half;                  // shfl index: 2*p + half
            int p = 0;
            for (; p + 8 <= pairs; p += 8) {
#define G(j, A) { \
                int cb = __shfl(cv, pb + 2 * (j)); \
                unsigned u = *(const unsigned*)(hbC + ((unsigned)cb + voff)); \
                f32x2 ww = {__uint_as_float(u << 16), __uint_as_float(u & 0xFFFF0000u)}; \
                A += ww; }
                G(0, a0)  G(1, a1)  G(2, a2)  G(3, a3)
                G(4, a4)  G(5, a5)  G(6, a6)  G(7, a7)
                pb += 16;
            }
            if (pairs & 4) {
                G(0, a0)  G(1, a1)  G(2, a2)  G(3, a3)
            }
#undef G
        }
        f32x2 s = ((a0 + a1) + (a2 + a3)) + ((a4 + a5) + (a6 + a7));
        float s0 = s.x + __shfl_xor(s.x, 32);
        float s1 = s.y + __shfl_xor(s.y, 32);
        float iv = invdeg[nodeC];
        if (!half) {
            int local = w * 4 + q;
            unsigned mo = (unsigned)bf16rne(s0 * iv) | ((unsigned)bf16rne(s1 * iv) << 16);
            int cb = l31 >> 2;
            meanT[local * 32 + ((cb ^ (local & 7)) << 2) + (l31 & 3)] = mo;
        }
    }
    __syncthreads();

    // ---------------- phase 2: dense, wave w -> output quadrant nt=w ----------------
    const int nt = w;
    // A mean fragments from LDS (swizzle-aware ds_read_b128)
    bf16x8 Am[2];
#pragma unroll
    for (int s = 0; s < 2; ++s) {
        int cb = s * 4 + kg;
        Am[s] = *(const bf16x8*)&meanT[l15 * 32 + ((cb ^ (l15 & 7)) << 2)];
    }
    // A own fragments from global (own input == gather input in SAGEConv)
    int arow = nb + l15; if (arow >= n) arow = n - 1;
    const unsigned short* orow = hb + (size_t)arow * 64 + kg * 8;
    bf16x8 Ao0 = *(const bf16x8*)(orow);
    bf16x8 Ao1 = *(const bf16x8*)(orow + 32);
    // B fragments (transient loads, L2-resident)
    const unsigned short* wrow = wcat + (nt * 16 + l15) * 128 + kg * 8;
    bf16x8 B0 = *(const bf16x8*)(wrow);
    bf16x8 B1 = *(const bf16x8*)(wrow + 32);
    bf16x8 B2 = *(const bf16x8*)(wrow + 64);
    bf16x8 B3 = *(const bf16x8*)(wrow + 96);

    float bc = bias[nt * 16 + l15];
    f32x4 a = {bc, bc, bc, bc};
    a = __builtin_amdgcn_mfma_f32_16x16x32_bf16(Am[0], B0, a, 0, 0, 0);
    a = __builtin_amdgcn_mfma_f32_16x16x32_bf16(Am[1], B1, a, 0, 0, 0);
    a = __builtin_amdgcn_mfma_f32_16x16x32_bf16(Ao0,  B2, a, 0, 0, 0);
    a = __builtin_amdgcn_mfma_f32_16x16x32_bf16(Ao1,  B3, a, 0, 0, 0);

    if constexpr (!HEAD) {
#pragma unroll
        for (int r = 0; r < 4; ++r) {
            int rw = nb + kg * 4 + r;
            float h = fmaxf(a[r], 0.0f);
            if (rw < n) houtb[(size_t)rw * 64 + nt * 16 + l15] = bf16rne(h);
        }
    } else {
        int bGlob = nt * 2 + (l15 >> 3);
        int n7 = l15 & 7;
#pragma unroll
        for (int r = 0; r < 4; ++r) {
            int m = kg * 4 + r;
            float h = fmaxf(a[r], 0.0f);
            hT[m * 64 + ((bGlob ^ (m & 7)) * 8) + n7] = bf16rne(h);
        }
        __syncthreads();
        if (w < 2) {
            bf16x8 hA[2];
#pragma unroll
            for (int s = 0; s < 2; ++s) {
                int kb = s * 4 + kg;
                hA[s] = *(const bf16x8*)(hT + l15 * 64 + ((kb ^ (l15 & 7)) * 8));
            }
            const unsigned short* hrow = whb + (w * 16 + l15) * 64 + kg * 8;
            bf16x8 H0 = *(const bf16x8*)(hrow);
            bf16x8 H1 = *(const bf16x8*)(hrow + 32);
            float bc2 = bh[w * 16 + l15];
            f32x4 a2 = {bc2, bc2, bc2, bc2};
            a2 = __builtin_amdgcn_mfma_f32_16x16x32_bf16(hA[0], H0, a2, 0, 0, 0);
            a2 = __builtin_amdgcn_mfma_f32_16x16x32_bf16(hA[1], H1, a2, 0, 0, 0);
#pragma unroll
            for (int r = 0; r < 4; ++r) {
                int rw = nb + kg * 4 + r;
                if (rw < n) outp[(size_t)rw * 32 + w * 16 + l15] = a2[r];
            }
        }
    }
}

extern "C" void kernel_launch(void* const* d_in, const int* in_sizes, int n_in,
                              void* d_out, int out_size, void* d_ws, size_t ws_size,
                              hipStream_t stream) {
    const float* x   = (const float*)d_in[0];
    const int* edges = (const int*)d_in[1];
    const float* w1l = (const float*)d_in[2];
    const float* b1  = (const float*)d_in[3];
    const float* w1r = (const float*)d_in[4];
    const float* w2l = (const float*)d_in[5];
    const float* b2  = (const float*)d_in[6];
    const float* w2r = (const float*)d_in[7];
    const float* wh  = (const float*)d_in[8];
    const float* bh  = (const float*)d_in[9];
    float* out = (float*)d_out;

    const int N = in_sizes[0] / D;   // 100000
    const int E = in_sizes[1] / 2;   // 1600000
    const int NR = (N + REG_SIZE - 1) >> REG_SHIFT;   // 391

    int* ws = (int*)d_ws;
    int*            flag     = ws + OFF_FLAG;
    int*            rcur     = ws + OFF_RCUR;
    int*            degP     = ws + OFF_DEG;
    int*            rowStartP= ws + OFF_ROWSTART;
    float*          inv      = (float*)(ws + OFF_INV);
    int*            colP     = ws + OFF_COL;
    int*            ebuf     = ws + OFF_EBUF;
    unsigned short* xb       = (unsigned short*)(ws + OFF_XB);
    unsigned short* h1b      = (unsigned short*)(ws + OFF_H1B);
    unsigned short* wcat1    = (unsigned short*)(ws + OFF_WC1);
    unsigned short* wcat2    = (unsigned short*)(ws + OFF_WC2);
    unsigned short* whb      = (unsigned short*)(ws + OFF_WHB);

    // ---- CSR build + prep (bin and prep fused into one dispatch) ----
    detect_init<<<1, 512, 0, stream>>>(edges, flag, rcur, NR);
    int bblocks = (E + BCHUNK - 1) / BCHUNK;                  // 391
    int n4 = N * D / 4;
    int pblocks = (n4 + 32 + 16384 + 2048 + 255) / 256;       // ~6323
    bin_prep<<<bblocks + pblocks, 256, 0, stream>>>(
        edges, flag, rcur, ebuf, E, NR, bblocks,
        x, xb, h1b, w1l, w1r, w2l, w2r, wh, wcat1, wcat2, whb, n4, N);
    build_csr<<<NR, 256, 0, stream>>>(ebuf, rcur, degP, rowStartP, inv, colP, N);

    int ntiles = (N + 15) / 16;   // 6250

    // ---- layer 1 (gather + dense fused) ----
    fused_layer<false><<<ntiles, 256, 0, stream>>>(
        xb, rowStartP, degP, colP, inv, wcat1, b1,
        h1b, nullptr, nullptr, nullptr, N);
    // ---- layer 2 + head (fused) ----
    fused_layer<true><<<ntiles, 256, 0, stream>>>(
        h1b, rowStartP, degP, colP, inv, wcat2, b2,
        nullptr, whb, bh, out, N);
}